// Round 9
// baseline (336.795 us; speedup 1.0000x reference)
//
#include <hip/hip_runtime.h>
#include <math.h>

#define NN 50000
#define EE 1600000
#define FIN 512
#define H1N 8
#define C2N 40
#define NEG 0.2f

// ---------------- bucketed CSR build ----------------
#define NB 391
#define CAPG 6144
#define PA_ITEMS 4096
#define NITEMS (EE + NN)
#define PA_BLOCKS ((NITEMS + PA_ITEMS - 1) / PA_ITEMS)   // 403
#define W1T_BLOCKS 32

// bf16 helpers
typedef __attribute__((ext_vector_type(8))) short bf16x8;
typedef __attribute__((ext_vector_type(4))) float f32x4;

__device__ inline short f2bf(float f) {
  unsigned int u = __float_as_uint(f);
  u += 0x7FFFu + ((u >> 16) & 1u);     // round-to-nearest-even
  return (short)(u >> 16);
}
__device__ inline unsigned int pack2bf(float lo, float hi) {
  return (unsigned int)(unsigned short)f2bf(lo) | ((unsigned int)(unsigned short)f2bf(hi) << 16);
}
__device__ inline float bflo(unsigned int v) { return __uint_as_float(v << 16); }
__device__ inline float bfhi(unsigned int v) { return __uint_as_float(v & 0xFFFF0000u); }

// passA: coarse binning with LDS staging; w1t transpose folded in as extra blocks.
__global__ __launch_bounds__(256) void passA_kernel(const int* __restrict__ ei,
    int* __restrict__ bucket_cnt, unsigned int* __restrict__ bucket_glob,
    const float* __restrict__ W1, short* __restrict__ WT) {
  int t = threadIdx.x;
  if (blockIdx.x >= PA_BLOCKS) {
    int base = (blockIdx.x - PA_BLOCKS) * 1024 + t * 4;
#pragma unroll
    for (int j = 0; j < 4; ++j) {
      int i = base + j;                   // i = n*512 + k
      int n = i >> 9, k = i & 511;
      WT[i] = f2bf(W1[k * 64 + n]);
    }
    return;
  }
  __shared__ int hist[NB];
  __shared__ int prefix[NB];
  __shared__ int cursor[NB];
  __shared__ int gbase[NB];
  __shared__ int scA[512], scB[512];
  __shared__ unsigned int staging[PA_ITEMS];
  int i0 = blockIdx.x * PA_ITEMS;
  int count = NITEMS - i0; if (count > PA_ITEMS) count = PA_ITEMS;

  for (int b = t; b < NB; b += 256) hist[b] = 0;
  __syncthreads();
  for (int j = t; j < count; j += 256) {
    int e = i0 + j;
    int dst = (e < EE) ? ei[EE + e] : (e - EE);
    atomicAdd(&hist[dst >> 7], 1);
  }
  __syncthreads();
  scA[t]       = (t < NB) ? hist[t] : 0;
  scA[t + 256] = (t + 256 < NB) ? hist[t + 256] : 0;
  __syncthreads();
  {
    int* pa = scA; int* pb = scB;
    for (int off = 1; off < 512; off <<= 1) {
      pb[t]       = pa[t]       + (t >= off ? pa[t - off] : 0);
      pb[t + 256] = pa[t + 256] + (t + 256 >= off ? pa[t + 256 - off] : 0);
      __syncthreads();
      int* tmp = pa; pa = pb; pb = tmp;
    }
    for (int b = t; b < NB; b += 256) {
      int ex = pa[b] - hist[b];
      prefix[b] = ex;
      cursor[b] = ex;
      if (hist[b] > 0) gbase[b] = atomicAdd(&bucket_cnt[b], hist[b]);
    }
  }
  __syncthreads();
  for (int j = t; j < count; j += 256) {
    int e = i0 + j;
    int src, dst;
    if (e < EE) { src = ei[e]; dst = ei[EE + e]; }
    else        { src = e - EE; dst = src; }
    int b = dst >> 7;
    unsigned int v = (unsigned int)src | ((unsigned int)(dst & 127) << 16)
                   | ((unsigned int)b << 23);
    int lp = atomicAdd(&cursor[b], 1);
    staging[lp] = v;
  }
  __syncthreads();
  for (int j = t; j < count; j += 256) {
    unsigned int v = staging[j];
    int b = (int)(v >> 23);
    int gpos = b * CAPG + gbase[b] + (j - prefix[b]);
    bucket_glob[gpos] = v;
  }
}

__global__ __launch_bounds__(512) void scan_buckets(const int* __restrict__ bucket_cnt,
    int* __restrict__ bucket_base, int* __restrict__ row_ptr_last) {
  __shared__ int scA[512], scB[512];
  int t = threadIdx.x;
  int v = (t < NB) ? bucket_cnt[t] : 0;
  scA[t] = v;
  __syncthreads();
  int* pa = scA; int* pb = scB;
  for (int off = 1; off < 512; off <<= 1) {
    pb[t] = pa[t] + (t >= off ? pa[t - off] : 0);
    __syncthreads();
    int* tmp = pa; pa = pb; pb = tmp;
  }
  if (t < NB) bucket_base[t] = pa[t] - v;
  if (t == NB - 1) *row_ptr_last = pa[t];
}

#define CAPB 6144
__global__ __launch_bounds__(256) void passB_kernel(const unsigned int* __restrict__ bucket_glob,
    const int* __restrict__ bucket_cnt, const int* __restrict__ bucket_base,
    int* __restrict__ row_ptr, int* __restrict__ col) {
  __shared__ int hist[128], pre[128], cur[128];
  __shared__ int scA[128], scB[128];
  __shared__ int sorted[CAPB];
  int b = blockIdx.x, t = threadIdx.x;
  int cnt = bucket_cnt[b];
  int base = bucket_base[b];
  const unsigned int* in = bucket_glob + (size_t)b * CAPG;
  if (t < 128) hist[t] = 0;
  __syncthreads();
  for (int j = t; j < cnt; j += 256) {
    int dl = (int)((in[j] >> 16) & 127u);
    atomicAdd(&hist[dl], 1);
  }
  __syncthreads();
  if (t < 128) scA[t] = hist[t];
  __syncthreads();
  {
    int* pa = scA; int* pb = scB;
    for (int off = 1; off < 128; off <<= 1) {
      if (t < 128) pb[t] = pa[t] + (t >= off ? pa[t - off] : 0);
      __syncthreads();
      int* tmp = pa; pa = pb; pb = tmp;
    }
    if (t < 128) {
      int ex = pa[t] - hist[t];
      pre[t] = ex;
      cur[t] = ex;
      int d = b * 128 + t;
      if (d < NN) row_ptr[d] = base + ex;
    }
  }
  __syncthreads();
  for (int j = t; j < cnt; j += 256) {
    unsigned int v = in[j];
    int dl = (int)((v >> 16) & 127u);
    int lp = atomicAdd(&cur[dl], 1);
    sorted[lp] = (int)(v & 0xFFFFu);
  }
  __syncthreads();
  for (int j = t; j < cnt; j += 256) col[base + j] = sorted[j];
}

// ---------------- GEMM1 (bf16 MFMA) + fused att1 ----------------

#define XS_STRIDE 136
#define HS_STRIDE 68
__global__ __launch_bounds__(256) void gemm1_kernel(const float* __restrict__ x,
    const short* __restrict__ WT, unsigned short* __restrict__ h1b,
    const float* __restrict__ att_src, const float* __restrict__ att_dst,
    float* __restrict__ asrc, float* __restrict__ adst) {
  __shared__ char smem[64 * XS_STRIDE * 2];   // 17408 B; aliased short/float
  short* xs = (short*)smem;
  float* hsf = (float*)smem;
  int t = threadIdx.x;
  int wave = t >> 6, lane = t & 63;
  int quad = lane >> 4, m = lane & 15;
  int row0 = blockIdx.x * 64;
  f32x4 acc[4] = {{0.f,0.f,0.f,0.f},{0.f,0.f,0.f,0.f},{0.f,0.f,0.f,0.f},{0.f,0.f,0.f,0.f}};
  for (int kc = 0; kc < 4; ++kc) {
    int k0 = kc * 128;
    __syncthreads();
#pragma unroll
    for (int jj = 0; jj < 8; ++jj) {
      int idx = jj * 256 + t;
      int row = idx >> 5, kq = idx & 31;
      int rr = row0 + row; if (rr >= NN) rr = NN - 1;
      float4 v = *(const float4*)(x + (size_t)rr * FIN + k0 + kq * 4);
      short4 s;
      s.x = f2bf(v.x); s.y = f2bf(v.y); s.z = f2bf(v.z); s.w = f2bf(v.w);
      *(short4*)&xs[row * XS_STRIDE + kq * 4] = s;
    }
    __syncthreads();
#pragma unroll
    for (int ks = 0; ks < 4; ++ks) {
      bf16x8 a = *(bf16x8*)&xs[(wave * 16 + m) * XS_STRIDE + ks * 32 + quad * 8];
#pragma unroll
      for (int tl = 0; tl < 4; ++tl) {
        bf16x8 b = *(const bf16x8*)(WT + (size_t)(tl * 16 + m) * 512 + k0 + ks * 32 + quad * 8);
        acc[tl] = __builtin_amdgcn_mfma_f32_16x16x32_bf16(a, b, acc[tl], 0, 0, 0);
      }
    }
  }
  __syncthreads();
  int rl0 = wave * 16 + quad * 4;
#pragma unroll
  for (int tl = 0; tl < 4; ++tl) {
#pragma unroll
    for (int r = 0; r < 4; ++r) {
      int rr = row0 + rl0 + r;
      if (rr < NN) h1b[(size_t)rr * 64 + tl * 16 + m] = (unsigned short)f2bf(acc[tl][r]);
      hsf[(rl0 + r) * HS_STRIDE + tl * 16 + m] = acc[tl][r];
    }
  }
  __syncthreads();
#pragma unroll
  for (int p = 0; p < 2; ++p) {
    int idx = p * 256 + t;
    int rl = idx >> 3, h = idx & 7;
    int rr = row0 + rl;
    if (rr < NN) {
      const float* hv = &hsf[rl * HS_STRIDE + h * 8];
      const float* as = att_src + h * 8;
      const float* ad = att_dst + h * 8;
      float s = 0.f, dd = 0.f;
#pragma unroll
      for (int c = 0; c < 8; ++c) { s = fmaf(hv[c], as[c], s); dd = fmaf(hv[c], ad[c], dd); }
      asrc[rr * 8 + h] = s;
      adst[rr * 8 + h] = dd;
    }
  }
}

// ---------------- layer-1 edge kernel (32 edges/iter) + fused gemm2/att2 ----------------
// lane = (j = lane>>3 edge slot, g = lane&7 = head). Per 32 edges: 4 col + 4 asrc +
// 4 uint4 h1b gathers all independent -> 12 VMEM in flight. Per-dst metadata hoisted.

__global__ __launch_bounds__(256) void l1_edge_kernel(const int* __restrict__ row_ptr,
    const int* __restrict__ col, const unsigned int* __restrict__ h1b,
    const float* __restrict__ asrc, const float* __restrict__ adst,
    const float* __restrict__ b1, const float* __restrict__ W2,
    const float* __restrict__ att_src2, const float* __restrict__ att_dst2,
    unsigned int* __restrict__ gb, float* __restrict__ asrc2, float* __restrict__ adst2) {
  __shared__ float w2s[64 * C2N];    // 10240 B
  __shared__ float hs[4][64];
  __shared__ float gs[4][48];
  int t = threadIdx.x;
  for (int i = t; i < 64 * C2N; i += 256) w2s[i] = W2[i];
  __syncthreads();
  int wave = t >> 6, lane = t & 63;
  int g = lane & 7, j = lane >> 3;
  int d0 = blockIdx.x * 16 + wave;
  // hoist metadata for this wave's 4 dsts (independent loads, one wait)
  int st[4], en[4]; float ad[4];
#pragma unroll
  for (int it = 0; it < 4; ++it) {
    int d = d0 + it * 4;
    if (d < NN) { st[it] = row_ptr[d]; en[it] = row_ptr[d + 1]; ad[it] = adst[d * 8 + g]; }
  }
#pragma unroll 1
  for (int iter = 0; iter < 4; ++iter) {
    int d = d0 + iter * 4;
    if (d >= NN) break;                    // no barriers below: safe divergence
    int start = st[iter], end = en[iter];
    float adst_h = ad[iter];
    float acc[8] = {0.f,0.f,0.f,0.f,0.f,0.f,0.f,0.f};
    float den = 0.f;
    for (int e = start; e < end; e += 32) {
      int iq[4], sq[4];
#pragma unroll
      for (int q = 0; q < 4; ++q) {
        iq[q] = e + 8 * q + j;
        int k = iq[q] < end ? iq[q] : end - 1;
        sq[q] = col[k];
      }
      float av[4];
#pragma unroll
      for (int q = 0; q < 4; ++q) av[q] = asrc[sq[q] * 8 + g];
      uint4 hv[4];
#pragma unroll
      for (int q = 0; q < 4; ++q) hv[q] = *(const uint4*)(h1b + (size_t)sq[q] * 32 + g * 4);
#pragma unroll
      for (int q = 0; q < 4; ++q) {
        float a = av[q] + adst_h;
        float lg = fmaxf(a, NEG * a);      // leaky_relu
        float ex = (iq[q] < end) ? __expf(lg) : 0.f;
        den += ex;
        acc[0] = fmaf(ex, bflo(hv[q].x), acc[0]);
        acc[1] = fmaf(ex, bfhi(hv[q].x), acc[1]);
        acc[2] = fmaf(ex, bflo(hv[q].y), acc[2]);
        acc[3] = fmaf(ex, bfhi(hv[q].y), acc[3]);
        acc[4] = fmaf(ex, bflo(hv[q].z), acc[4]);
        acc[5] = fmaf(ex, bfhi(hv[q].z), acc[5]);
        acc[6] = fmaf(ex, bflo(hv[q].w), acc[6]);
        acc[7] = fmaf(ex, bfhi(hv[q].w), acc[7]);
      }
    }
#pragma unroll
    for (int off = 8; off <= 32; off <<= 1) {
      den += __shfl_xor(den, off);
#pragma unroll
      for (int c = 0; c < 8; ++c) acc[c] += __shfl_xor(acc[c], off);
    }
    float inv = 1.f / den;
    if (j == 0) {
      float4 b1a = *(const float4*)(b1 + g * 8);
      float4 b1b = *(const float4*)(b1 + g * 8 + 4);
      float4 h0, h1v;
      h0.x = fmaxf(fmaf(acc[0], inv, b1a.x), 0.f);
      h0.y = fmaxf(fmaf(acc[1], inv, b1a.y), 0.f);
      h0.z = fmaxf(fmaf(acc[2], inv, b1a.z), 0.f);
      h0.w = fmaxf(fmaf(acc[3], inv, b1a.w), 0.f);
      h1v.x = fmaxf(fmaf(acc[4], inv, b1b.x), 0.f);
      h1v.y = fmaxf(fmaf(acc[5], inv, b1b.y), 0.f);
      h1v.z = fmaxf(fmaf(acc[6], inv, b1b.z), 0.f);
      h1v.w = fmaxf(fmaf(acc[7], inv, b1b.w), 0.f);
      *(float4*)&hs[wave][g * 8]     = h0;
      *(float4*)&hs[wave][g * 8 + 4] = h1v;
    }
    // fused gemm2 (same-wave LDS, no block barrier)
    int c = lane;
    float gacc = 0.f;
    if (c < C2N) {
#pragma unroll
      for (int k = 0; k < 64; ++k) gacc = fmaf(hs[wave][k], w2s[k * C2N + c], gacc);
    }
    float asv = (c < C2N) ? gacc * att_src2[c] : 0.f;
    float adv = (c < C2N) ? gacc * att_dst2[c] : 0.f;
#pragma unroll
    for (int off = 32; off >= 1; off >>= 1) {
      asv += __shfl_xor(asv, off);
      adv += __shfl_xor(adv, off);
    }
    if (lane == 0) { asrc2[d] = asv; adst2[d] = adv; }
    if (c < C2N) gs[wave][c] = gacc;
    if (lane < 20) gb[(size_t)d * 20 + lane] = pack2bf(gs[wave][2 * lane], gs[wave][2 * lane + 1]);
  }
}

// ---------------- layer-2 edge kernel (32 edges/iter) + log_softmax ----------------

__global__ __launch_bounds__(256) void l2_edge_kernel(const int* __restrict__ row_ptr,
    const int* __restrict__ col, const unsigned int* __restrict__ gb,
    const float* __restrict__ asrc2, const float* __restrict__ adst2,
    const float* __restrict__ b2, float* __restrict__ out) {
  int t = threadIdx.x;
  int d = (blockIdx.x * 256 + t) >> 6;
  if (d >= NN) return;
  int lane = t & 63;
  int g = lane & 7, j = lane >> 3;
  int gq = (g < 5) ? g : 4;
  bool act = g < 5;
  int start = row_ptr[d], end = row_ptr[d + 1];
  float adst_d = adst2[d];
  float acc[8] = {0.f,0.f,0.f,0.f,0.f,0.f,0.f,0.f};
  float den = 0.f;
  for (int e = start; e < end; e += 32) {
    int iq[4], sq[4];
#pragma unroll
    for (int q = 0; q < 4; ++q) {
      iq[q] = e + 8 * q + j;
      int k = iq[q] < end ? iq[q] : end - 1;
      sq[q] = col[k];
    }
    float av[4];
#pragma unroll
    for (int q = 0; q < 4; ++q) av[q] = asrc2[sq[q]];
    uint4 gv[4];
#pragma unroll
    for (int q = 0; q < 4; ++q) gv[q] = *(const uint4*)(gb + (size_t)sq[q] * 20 + gq * 4);
#pragma unroll
    for (int q = 0; q < 4; ++q) {
      float a = av[q] + adst_d;
      float lg = fmaxf(a, NEG * a);
      float ex = (iq[q] < end) ? __expf(lg) : 0.f;
      den += ex;
      acc[0] = fmaf(ex, bflo(gv[q].x), acc[0]);
      acc[1] = fmaf(ex, bfhi(gv[q].x), acc[1]);
      acc[2] = fmaf(ex, bflo(gv[q].y), acc[2]);
      acc[3] = fmaf(ex, bfhi(gv[q].y), acc[3]);
      acc[4] = fmaf(ex, bflo(gv[q].z), acc[4]);
      acc[5] = fmaf(ex, bfhi(gv[q].z), acc[5]);
      acc[6] = fmaf(ex, bflo(gv[q].w), acc[6]);
      acc[7] = fmaf(ex, bfhi(gv[q].w), acc[7]);
    }
  }
#pragma unroll
  for (int off = 8; off <= 32; off <<= 1) {
    den += __shfl_xor(den, off);
#pragma unroll
    for (int c = 0; c < 8; ++c) acc[c] += __shfl_xor(acc[c], off);
  }
  float inv = 1.f / den;
  float4 b2a = *(const float4*)(b2 + gq * 8);
  float4 b2b = *(const float4*)(b2 + gq * 8 + 4);
  float o[8];
  o[0] = fmaf(acc[0], inv, b2a.x); o[1] = fmaf(acc[1], inv, b2a.y);
  o[2] = fmaf(acc[2], inv, b2a.z); o[3] = fmaf(acc[3], inv, b2a.w);
  o[4] = fmaf(acc[4], inv, b2b.x); o[5] = fmaf(acc[5], inv, b2b.y);
  o[6] = fmaf(acc[6], inv, b2b.z); o[7] = fmaf(acc[7], inv, b2b.w);
  float m = -INFINITY;
  if (act) {
#pragma unroll
    for (int i = 0; i < 8; ++i) m = fmaxf(m, o[i]);
  }
#pragma unroll
  for (int off = 1; off <= 4; off <<= 1) m = fmaxf(m, __shfl_xor(m, off));
  float es = 0.f;
  if (act) {
#pragma unroll
    for (int i = 0; i < 8; ++i) es += __expf(o[i] - m);
  }
#pragma unroll
  for (int off = 1; off <= 4; off <<= 1) es += __shfl_xor(es, off);
  float mls = m + logf(es);
  if (act && j == 0) {
    float4 r0 = make_float4(o[0] - mls, o[1] - mls, o[2] - mls, o[3] - mls);
    float4 r1 = make_float4(o[4] - mls, o[5] - mls, o[6] - mls, o[7] - mls);
    *(float4*)(out + (size_t)d * C2N + g * 8)     = r0;
    *(float4*)(out + (size_t)d * C2N + g * 8 + 4) = r1;
  }
}

// ---------------- launch ----------------

extern "C" void kernel_launch(void* const* d_in, const int* in_sizes, int n_in,
                              void* d_out, int out_size, void* d_ws, size_t ws_size,
                              hipStream_t stream) {
  const float* x        = (const float*)d_in[0];
  const int*   ei       = (const int*)d_in[1];
  const float* W1       = (const float*)d_in[2];
  const float* att_src1 = (const float*)d_in[3];
  const float* att_dst1 = (const float*)d_in[4];
  const float* b1       = (const float*)d_in[5];
  const float* W2       = (const float*)d_in[6];
  const float* att_src2 = (const float*)d_in[7];
  const float* att_dst2 = (const float*)d_in[8];
  const float* b2       = (const float*)d_in[9];
  float* out = (float*)d_out;

  char* ws = (char*)d_ws;
  size_t off = 0;
  auto alloc = [&](size_t n_elem) {
    void* p = ws + off;
    off = (off + n_elem * 4 + 255) & ~(size_t)255;
    return p;
  };
  unsigned int* h1b = (unsigned int*)alloc((size_t)NN * 32);      // bf16 packed [N][32]
  unsigned int* gb  = (unsigned int*)alloc((size_t)NN * 20 + 16); // bf16 packed [N][20] + slack
  unsigned int* bucket_glob = (unsigned int*)alloc((size_t)NB * CAPG);
  float* asrc1 = (float*)alloc((size_t)NN * 8);
  float* adst1 = (float*)alloc((size_t)NN * 8);
  float* asrc2 = (float*)alloc(NN);
  float* adst2 = (float*)alloc(NN);
  int* row_ptr = (int*)alloc(NN + 1);
  int* colv    = (int*)alloc(EE + NN);
  int* bucket_cnt  = (int*)alloc(NB);
  int* bucket_base = (int*)alloc(NB);
  short* w1t   = (short*)alloc(64 * 512 / 2);

  hipMemsetAsync(bucket_cnt, 0, NB * 4, stream);
  passA_kernel<<<PA_BLOCKS + W1T_BLOCKS, 256, 0, stream>>>(ei, bucket_cnt, bucket_glob, W1, w1t);
  scan_buckets<<<1, 512, 0, stream>>>(bucket_cnt, bucket_base, row_ptr + NN);
  passB_kernel<<<NB, 256, 0, stream>>>(bucket_glob, bucket_cnt, bucket_base, row_ptr, colv);

  gemm1_kernel<<<(NN + 63) / 64, 256, 0, stream>>>(x, w1t, (unsigned short*)h1b,
                                                   att_src1, att_dst1, asrc1, adst1);
  l1_edge_kernel<<<(NN + 15) / 16, 256, 0, stream>>>(row_ptr, colv, h1b, asrc1, adst1,
                                                     b1, W2, att_src2, att_dst2,
                                                     gb, asrc2, adst2);
  l2_edge_kernel<<<(NN * 64 + 255) / 256, 256, 0, stream>>>(row_ptr, colv, gb, asrc2, adst2, b2, out);
}

// Round 10
// 326.764 us; speedup vs baseline: 1.0307x; 1.0307x over previous
//
#include <hip/hip_runtime.h>
#include <math.h>

#define NN 50000
#define EE 1600000
#define FIN 512
#define H1N 8
#define C2N 40
#define NEG 0.2f

// ---------------- bucketed CSR build ----------------
#define NB 391
#define CAPG 6144
#define PA_ITEMS 4096
#define NITEMS (EE + NN)
#define PA_BLOCKS ((NITEMS + PA_ITEMS - 1) / PA_ITEMS)   // 403
#define W1T_BLOCKS 32

// bf16 helpers
typedef __attribute__((ext_vector_type(8))) short bf16x8;
typedef __attribute__((ext_vector_type(4))) float f32x4;

__device__ inline short f2bf(float f) {
  unsigned int u = __float_as_uint(f);
  u += 0x7FFFu + ((u >> 16) & 1u);     // round-to-nearest-even
  return (short)(u >> 16);
}
__device__ inline unsigned int pack2bf(float lo, float hi) {
  return (unsigned int)(unsigned short)f2bf(lo) | ((unsigned int)(unsigned short)f2bf(hi) << 16);
}
__device__ inline float bflo(unsigned int v) { return __uint_as_float(v << 16); }
__device__ inline float bfhi(unsigned int v) { return __uint_as_float(v & 0xFFFF0000u); }

// passA: coarse binning with LDS staging; dst stashed in VGPRs (single ei[dst] read);
// w1t transpose folded in as extra blocks.
__global__ __launch_bounds__(256) void passA_kernel(const int* __restrict__ ei,
    int* __restrict__ bucket_cnt, unsigned int* __restrict__ bucket_glob,
    const float* __restrict__ W1, short* __restrict__ WT) {
  int t = threadIdx.x;
  if (blockIdx.x >= PA_BLOCKS) {
    int base = (blockIdx.x - PA_BLOCKS) * 1024 + t * 4;
#pragma unroll
    for (int j = 0; j < 4; ++j) {
      int i = base + j;                   // i = n*512 + k
      int n = i >> 9, k = i & 511;
      WT[i] = f2bf(W1[k * 64 + n]);
    }
    return;
  }
  __shared__ int hist[NB];
  __shared__ int prefix[NB];
  __shared__ int cursor[NB];
  __shared__ int gbase[NB];
  __shared__ int scA[512], scB[512];
  __shared__ unsigned int staging[PA_ITEMS];
  int i0 = blockIdx.x * PA_ITEMS;
  int count = NITEMS - i0; if (count > PA_ITEMS) count = PA_ITEMS;

  for (int b = t; b < NB; b += 256) hist[b] = 0;
  __syncthreads();
  // phase 1: histogram; stash dst in registers (16 per thread)
  int dstv[16];
#pragma unroll
  for (int ii = 0; ii < 16; ++ii) {
    int jj = ii * 256 + t;
    if (jj < count) {
      int e = i0 + jj;
      int dst = (e < EE) ? ei[EE + e] : (e - EE);
      dstv[ii] = dst;
      atomicAdd(&hist[dst >> 7], 1);
    }
  }
  __syncthreads();
  scA[t]       = (t < NB) ? hist[t] : 0;
  scA[t + 256] = (t + 256 < NB) ? hist[t + 256] : 0;
  __syncthreads();
  {
    int* pa = scA; int* pb = scB;
    for (int off = 1; off < 512; off <<= 1) {
      pb[t]       = pa[t]       + (t >= off ? pa[t - off] : 0);
      pb[t + 256] = pa[t + 256] + (t + 256 >= off ? pa[t + 256 - off] : 0);
      __syncthreads();
      int* tmp = pa; pa = pb; pb = tmp;
    }
    for (int b = t; b < NB; b += 256) {
      int ex = pa[b] - hist[b];
      prefix[b] = ex;
      cursor[b] = ex;
      if (hist[b] > 0) gbase[b] = atomicAdd(&bucket_cnt[b], hist[b]);
    }
  }
  __syncthreads();
  // phase 3: stage grouped by bucket (src loaded here; dst from registers)
#pragma unroll
  for (int ii = 0; ii < 16; ++ii) {
    int jj = ii * 256 + t;
    if (jj < count) {
      int e = i0 + jj;
      int src = (e < EE) ? ei[e] : (e - EE);
      int dst = dstv[ii];
      int b = dst >> 7;
      unsigned int v = (unsigned int)src | ((unsigned int)(dst & 127) << 16)
                     | ((unsigned int)b << 23);
      int lp = atomicAdd(&cursor[b], 1);
      staging[lp] = v;
    }
  }
  __syncthreads();
  for (int j = t; j < count; j += 256) {
    unsigned int v = staging[j];
    int b = (int)(v >> 23);
    int gpos = b * CAPG + gbase[b] + (j - prefix[b]);
    bucket_glob[gpos] = v;
  }
}

// passB: inline 391-bucket prefix scan (replaces scan_buckets kernel), then per-bucket
// counting sort of 128 local dsts in LDS, emit row_ptr + coalesced col.
#define CAPB 6144
__global__ __launch_bounds__(256) void passB_kernel(const unsigned int* __restrict__ bucket_glob,
    const int* __restrict__ bucket_cnt, int* __restrict__ row_ptr, int* __restrict__ col) {
  __shared__ int scA[512], scB[512];
  __shared__ int hist[128], cur[128];
  __shared__ int sorted[CAPB];
  int b = blockIdx.x, t = threadIdx.x;
  // inline inclusive scan over all bucket counts
  scA[t]       = (t < NB) ? bucket_cnt[t] : 0;
  scA[t + 256] = (t + 256 < NB) ? bucket_cnt[t + 256] : 0;
  __syncthreads();
  int* pa = scA; int* pb = scB;
  for (int off = 1; off < 512; off <<= 1) {
    pb[t]       = pa[t]       + (t >= off ? pa[t - off] : 0);
    pb[t + 256] = pa[t + 256] + (t + 256 >= off ? pa[t + 256 - off] : 0);
    __syncthreads();
    int* tmp = pa; pa = pb; pb = tmp;
  }
  int cnt = bucket_cnt[b];
  int base = pa[b] - cnt;                       // exclusive prefix for this bucket
  if (b == 0 && t == 0) row_ptr[NN] = pa[NB - 1];
  __syncthreads();                              // done with pa before reusing scA/scB
  const unsigned int* in = bucket_glob + (size_t)b * CAPG;
  if (t < 128) hist[t] = 0;
  __syncthreads();
  for (int j = t; j < cnt; j += 256) {
    int dl = (int)((in[j] >> 16) & 127u);
    atomicAdd(&hist[dl], 1);
  }
  __syncthreads();
  if (t < 128) scA[t] = hist[t];
  __syncthreads();
  {
    int* qa = scA; int* qb = scB;
    for (int off = 1; off < 128; off <<= 1) {
      if (t < 128) qb[t] = qa[t] + (t >= off ? qa[t - off] : 0);
      __syncthreads();
      int* tmp = qa; qa = qb; qb = tmp;
    }
    if (t < 128) {
      int ex = qa[t] - hist[t];
      cur[t] = ex;
      int d = b * 128 + t;
      if (d < NN) row_ptr[d] = base + ex;
    }
  }
  __syncthreads();
  for (int j = t; j < cnt; j += 256) {
    unsigned int v = in[j];
    int dl = (int)((v >> 16) & 127u);
    int lp = atomicAdd(&cur[dl], 1);
    sorted[lp] = (int)(v & 0xFFFFu);
  }
  __syncthreads();
  for (int j = t; j < cnt; j += 256) col[base + j] = sorted[j];
}

// ---------------- GEMM1 (bf16 MFMA) + fused att1 ----------------

#define XS_STRIDE 136
#define HS_STRIDE 68
__global__ __launch_bounds__(256) void gemm1_kernel(const float* __restrict__ x,
    const short* __restrict__ WT, unsigned short* __restrict__ h1b,
    const float* __restrict__ att_src, const float* __restrict__ att_dst,
    float* __restrict__ asrc, float* __restrict__ adst) {
  __shared__ char smem[64 * XS_STRIDE * 2];   // 17408 B; aliased short/float
  short* xs = (short*)smem;
  float* hsf = (float*)smem;
  int t = threadIdx.x;
  int wave = t >> 6, lane = t & 63;
  int quad = lane >> 4, m = lane & 15;
  int row0 = blockIdx.x * 64;
  f32x4 acc[4] = {{0.f,0.f,0.f,0.f},{0.f,0.f,0.f,0.f},{0.f,0.f,0.f,0.f},{0.f,0.f,0.f,0.f}};
  for (int kc = 0; kc < 4; ++kc) {
    int k0 = kc * 128;
    __syncthreads();
#pragma unroll
    for (int jj = 0; jj < 8; ++jj) {
      int idx = jj * 256 + t;
      int row = idx >> 5, kq = idx & 31;
      int rr = row0 + row; if (rr >= NN) rr = NN - 1;
      float4 v = *(const float4*)(x + (size_t)rr * FIN + k0 + kq * 4);
      short4 s;
      s.x = f2bf(v.x); s.y = f2bf(v.y); s.z = f2bf(v.z); s.w = f2bf(v.w);
      *(short4*)&xs[row * XS_STRIDE + kq * 4] = s;
    }
    __syncthreads();
#pragma unroll
    for (int ks = 0; ks < 4; ++ks) {
      bf16x8 a = *(bf16x8*)&xs[(wave * 16 + m) * XS_STRIDE + ks * 32 + quad * 8];
#pragma unroll
      for (int tl = 0; tl < 4; ++tl) {
        bf16x8 b = *(const bf16x8*)(WT + (size_t)(tl * 16 + m) * 512 + k0 + ks * 32 + quad * 8);
        acc[tl] = __builtin_amdgcn_mfma_f32_16x16x32_bf16(a, b, acc[tl], 0, 0, 0);
      }
    }
  }
  __syncthreads();
  int rl0 = wave * 16 + quad * 4;
#pragma unroll
  for (int tl = 0; tl < 4; ++tl) {
#pragma unroll
    for (int r = 0; r < 4; ++r) {
      int rr = row0 + rl0 + r;
      if (rr < NN) h1b[(size_t)rr * 64 + tl * 16 + m] = (unsigned short)f2bf(acc[tl][r]);
      hsf[(rl0 + r) * HS_STRIDE + tl * 16 + m] = acc[tl][r];
    }
  }
  __syncthreads();
#pragma unroll
  for (int p = 0; p < 2; ++p) {
    int idx = p * 256 + t;
    int rl = idx >> 3, h = idx & 7;
    int rr = row0 + rl;
    if (rr < NN) {
      const float* hv = &hsf[rl * HS_STRIDE + h * 8];
      const float* as = att_src + h * 8;
      const float* ad = att_dst + h * 8;
      float s = 0.f, dd = 0.f;
#pragma unroll
      for (int c = 0; c < 8; ++c) { s = fmaf(hv[c], as[c], s); dd = fmaf(hv[c], ad[c], dd); }
      asrc[rr * 8 + h] = s;
      adst[rr * 8 + h] = dd;
    }
  }
}

// ---------------- layer-1 edge kernel (16 edges/iter, uniform tail guard) + fused gemm2/att2 ----------------
// lane = (j = lane>>3 edge slot, g = lane&7 = head). Group of 8 edges = 3 VMEM/lane.
// 2nd group guarded by wave-uniform (e+8 < end) -> s_cbranch, no divergence cost.

__global__ __launch_bounds__(256) void l1_edge_kernel(const int* __restrict__ row_ptr,
    const int* __restrict__ col, const unsigned int* __restrict__ h1b,
    const float* __restrict__ asrc, const float* __restrict__ adst,
    const float* __restrict__ b1, const float* __restrict__ W2,
    const float* __restrict__ att_src2, const float* __restrict__ att_dst2,
    unsigned int* __restrict__ gb, float* __restrict__ asrc2, float* __restrict__ adst2) {
  __shared__ float w2s[64 * C2N];    // 10240 B
  __shared__ float hs[4][64];
  __shared__ float gs[4][48];
  int t = threadIdx.x;
  for (int i = t; i < 64 * C2N; i += 256) w2s[i] = W2[i];
  __syncthreads();
  int wave = t >> 6, lane = t & 63;
  int g = lane & 7, j = lane >> 3;
#pragma unroll 1
  for (int iter = 0; iter < 4; ++iter) {
    int d = blockIdx.x * 16 + iter * 4 + wave;
    if (d >= NN) break;                    // no barriers below: safe divergence
    int start = row_ptr[d], end = row_ptr[d + 1];
    float adst_h = adst[d * 8 + g];
    float acc[8] = {0.f,0.f,0.f,0.f,0.f,0.f,0.f,0.f};
    float den = 0.f;
    for (int e = start; e < end; e += 16) {
      bool two = (e + 8) < end;            // wave-uniform
      int i1 = e + j;
      int k1 = i1 < end ? i1 : end - 1;
      int s1 = col[k1];
      int s2 = 0;
      if (two) {
        int i2 = e + 8 + j;
        int k2 = i2 < end ? i2 : end - 1;
        s2 = col[k2];
      }
      float av1 = asrc[s1 * 8 + g];
      uint4 hv1 = *(const uint4*)(h1b + (size_t)s1 * 32 + g * 4);
      float av2 = 0.f;
      uint4 hv2 = make_uint4(0u, 0u, 0u, 0u);
      if (two) {
        av2 = asrc[s2 * 8 + g];
        hv2 = *(const uint4*)(h1b + (size_t)s2 * 32 + g * 4);
      }
      float a1 = av1 + adst_h, a2 = av2 + adst_h;
      float lg1 = fmaxf(a1, NEG * a1);     // leaky_relu
      float lg2 = fmaxf(a2, NEG * a2);
      float ex1 = (i1 < end) ? __expf(lg1) : 0.f;
      float ex2 = (two && (e + 8 + j) < end) ? __expf(lg2) : 0.f;
      den += ex1 + ex2;
      acc[0] = fmaf(ex1, bflo(hv1.x), acc[0]); acc[0] = fmaf(ex2, bflo(hv2.x), acc[0]);
      acc[1] = fmaf(ex1, bfhi(hv1.x), acc[1]); acc[1] = fmaf(ex2, bfhi(hv2.x), acc[1]);
      acc[2] = fmaf(ex1, bflo(hv1.y), acc[2]); acc[2] = fmaf(ex2, bflo(hv2.y), acc[2]);
      acc[3] = fmaf(ex1, bfhi(hv1.y), acc[3]); acc[3] = fmaf(ex2, bfhi(hv2.y), acc[3]);
      acc[4] = fmaf(ex1, bflo(hv1.z), acc[4]); acc[4] = fmaf(ex2, bflo(hv2.z), acc[4]);
      acc[5] = fmaf(ex1, bfhi(hv1.z), acc[5]); acc[5] = fmaf(ex2, bfhi(hv2.z), acc[5]);
      acc[6] = fmaf(ex1, bflo(hv1.w), acc[6]); acc[6] = fmaf(ex2, bflo(hv2.w), acc[6]);
      acc[7] = fmaf(ex1, bfhi(hv1.w), acc[7]); acc[7] = fmaf(ex2, bfhi(hv2.w), acc[7]);
    }
#pragma unroll
    for (int off = 8; off <= 32; off <<= 1) {
      den += __shfl_xor(den, off);
#pragma unroll
      for (int c = 0; c < 8; ++c) acc[c] += __shfl_xor(acc[c], off);
    }
    float inv = 1.f / den;
    if (j == 0) {
      float4 b1a = *(const float4*)(b1 + g * 8);
      float4 b1b = *(const float4*)(b1 + g * 8 + 4);
      float4 h0, h1v;
      h0.x = fmaxf(fmaf(acc[0], inv, b1a.x), 0.f);
      h0.y = fmaxf(fmaf(acc[1], inv, b1a.y), 0.f);
      h0.z = fmaxf(fmaf(acc[2], inv, b1a.z), 0.f);
      h0.w = fmaxf(fmaf(acc[3], inv, b1a.w), 0.f);
      h1v.x = fmaxf(fmaf(acc[4], inv, b1b.x), 0.f);
      h1v.y = fmaxf(fmaf(acc[5], inv, b1b.y), 0.f);
      h1v.z = fmaxf(fmaf(acc[6], inv, b1b.z), 0.f);
      h1v.w = fmaxf(fmaf(acc[7], inv, b1b.w), 0.f);
      *(float4*)&hs[wave][g * 8]     = h0;
      *(float4*)&hs[wave][g * 8 + 4] = h1v;
    }
    // fused gemm2 (same-wave LDS, no block barrier)
    int c = lane;
    float gacc = 0.f;
    if (c < C2N) {
#pragma unroll
      for (int k = 0; k < 64; ++k) gacc = fmaf(hs[wave][k], w2s[k * C2N + c], gacc);
    }
    float asv = (c < C2N) ? gacc * att_src2[c] : 0.f;
    float adv = (c < C2N) ? gacc * att_dst2[c] : 0.f;
#pragma unroll
    for (int off = 32; off >= 1; off >>= 1) {
      asv += __shfl_xor(asv, off);
      adv += __shfl_xor(adv, off);
    }
    if (lane == 0) { asrc2[d] = asv; adst2[d] = adv; }
    if (c < C2N) gs[wave][c] = gacc;
    if (lane < 20) gb[(size_t)d * 20 + lane] = pack2bf(gs[wave][2 * lane], gs[wave][2 * lane + 1]);
  }
}

// ---------------- layer-2 edge kernel (16 edges/iter, uniform tail guard) + log_softmax ----------------

__global__ __launch_bounds__(256) void l2_edge_kernel(const int* __restrict__ row_ptr,
    const int* __restrict__ col, const unsigned int* __restrict__ gb,
    const float* __restrict__ asrc2, const float* __restrict__ adst2,
    const float* __restrict__ b2, float* __restrict__ out) {
  int t = threadIdx.x;
  int d = (blockIdx.x * 256 + t) >> 6;
  if (d >= NN) return;
  int lane = t & 63;
  int g = lane & 7, j = lane >> 3;
  int gq = (g < 5) ? g : 4;
  bool act = g < 5;
  int start = row_ptr[d], end = row_ptr[d + 1];
  float adst_d = adst2[d];
  float acc[8] = {0.f,0.f,0.f,0.f,0.f,0.f,0.f,0.f};
  float den = 0.f;
  for (int e = start; e < end; e += 16) {
    bool two = (e + 8) < end;              // wave-uniform
    int i1 = e + j;
    int k1 = i1 < end ? i1 : end - 1;
    int s1 = col[k1];
    int s2 = 0;
    if (two) {
      int i2 = e + 8 + j;
      int k2 = i2 < end ? i2 : end - 1;
      s2 = col[k2];
    }
    float av1 = asrc2[s1];
    uint4 g1 = *(const uint4*)(gb + (size_t)s1 * 20 + gq * 4);
    float av2 = 0.f;
    uint4 g2 = make_uint4(0u, 0u, 0u, 0u);
    if (two) {
      av2 = asrc2[s2];
      g2 = *(const uint4*)(gb + (size_t)s2 * 20 + gq * 4);
    }
    float a1 = av1 + adst_d, a2 = av2 + adst_d;
    float lg1 = fmaxf(a1, NEG * a1);
    float lg2 = fmaxf(a2, NEG * a2);
    float ex1 = (i1 < end) ? __expf(lg1) : 0.f;
    float ex2 = (two && (e + 8 + j) < end) ? __expf(lg2) : 0.f;
    den += ex1 + ex2;
    acc[0] = fmaf(ex1, bflo(g1.x), acc[0]); acc[0] = fmaf(ex2, bflo(g2.x), acc[0]);
    acc[1] = fmaf(ex1, bfhi(g1.x), acc[1]); acc[1] = fmaf(ex2, bfhi(g2.x), acc[1]);
    acc[2] = fmaf(ex1, bflo(g1.y), acc[2]); acc[2] = fmaf(ex2, bflo(g2.y), acc[2]);
    acc[3] = fmaf(ex1, bfhi(g1.y), acc[3]); acc[3] = fmaf(ex2, bfhi(g2.y), acc[3]);
    acc[4] = fmaf(ex1, bflo(g1.z), acc[4]); acc[4] = fmaf(ex2, bflo(g2.z), acc[4]);
    acc[5] = fmaf(ex1, bfhi(g1.z), acc[5]); acc[5] = fmaf(ex2, bfhi(g2.z), acc[5]);
    acc[6] = fmaf(ex1, bflo(g1.w), acc[6]); acc[6] = fmaf(ex2, bflo(g2.w), acc[6]);
    acc[7] = fmaf(ex1, bfhi(g1.w), acc[7]); acc[7] = fmaf(ex2, bfhi(g2.w), acc[7]);
  }
#pragma unroll
  for (int off = 8; off <= 32; off <<= 1) {
    den += __shfl_xor(den, off);
#pragma unroll
    for (int c = 0; c < 8; ++c) acc[c] += __shfl_xor(acc[c], off);
  }
  float inv = 1.f / den;
  float4 b2a = *(const float4*)(b2 + gq * 8);
  float4 b2b = *(const float4*)(b2 + gq * 8 + 4);
  float o[8];
  o[0] = fmaf(acc[0], inv, b2a.x); o[1] = fmaf(acc[1], inv, b2a.y);
  o[2] = fmaf(acc[2], inv, b2a.z); o[3] = fmaf(acc[3], inv, b2a.w);
  o[4] = fmaf(acc[4], inv, b2b.x); o[5] = fmaf(acc[5], inv, b2b.y);
  o[6] = fmaf(acc[6], inv, b2b.z); o[7] = fmaf(acc[7], inv, b2b.w);
  float m = -INFINITY;
  if (act) {
#pragma unroll
    for (int i = 0; i < 8; ++i) m = fmaxf(m, o[i]);
  }
#pragma unroll
  for (int off = 1; off <= 4; off <<= 1) m = fmaxf(m, __shfl_xor(m, off));
  float es = 0.f;
  if (act) {
#pragma unroll
    for (int i = 0; i < 8; ++i) es += __expf(o[i] - m);
  }
#pragma unroll
  for (int off = 1; off <= 4; off <<= 1) es += __shfl_xor(es, off);
  float mls = m + logf(es);
  if (act && j == 0) {
    float4 r0 = make_float4(o[0] - mls, o[1] - mls, o[2] - mls, o[3] - mls);
    float4 r1 = make_float4(o[4] - mls, o[5] - mls, o[6] - mls, o[7] - mls);
    *(float4*)(out + (size_t)d * C2N + g * 8)     = r0;
    *(float4*)(out + (size_t)d * C2N + g * 8 + 4) = r1;
  }
}

// ---------------- launch ----------------

extern "C" void kernel_launch(void* const* d_in, const int* in_sizes, int n_in,
                              void* d_out, int out_size, void* d_ws, size_t ws_size,
                              hipStream_t stream) {
  const float* x        = (const float*)d_in[0];
  const int*   ei       = (const int*)d_in[1];
  const float* W1       = (const float*)d_in[2];
  const float* att_src1 = (const float*)d_in[3];
  const float* att_dst1 = (const float*)d_in[4];
  const float* b1       = (const float*)d_in[5];
  const float* W2       = (const float*)d_in[6];
  const float* att_src2 = (const float*)d_in[7];
  const float* att_dst2 = (const float*)d_in[8];
  const float* b2       = (const float*)d_in[9];
  float* out = (float*)d_out;

  char* ws = (char*)d_ws;
  size_t off = 0;
  auto alloc = [&](size_t n_elem) {
    void* p = ws + off;
    off = (off + n_elem * 4 + 255) & ~(size_t)255;
    return p;
  };
  unsigned int* h1b = (unsigned int*)alloc((size_t)NN * 32);      // bf16 packed [N][32]
  unsigned int* gb  = (unsigned int*)alloc((size_t)NN * 20 + 16); // bf16 packed [N][20] + slack
  unsigned int* bucket_glob = (unsigned int*)alloc((size_t)NB * CAPG);
  float* asrc1 = (float*)alloc((size_t)NN * 8);
  float* adst1 = (float*)alloc((size_t)NN * 8);
  float* asrc2 = (float*)alloc(NN);
  float* adst2 = (float*)alloc(NN);
  int* row_ptr = (int*)alloc(NN + 1);
  int* colv    = (int*)alloc(EE + NN);
  int* bucket_cnt  = (int*)alloc(NB);
  short* w1t   = (short*)alloc(64 * 512 / 2);

  hipMemsetAsync(bucket_cnt, 0, NB * 4, stream);
  passA_kernel<<<PA_BLOCKS + W1T_BLOCKS, 256, 0, stream>>>(ei, bucket_cnt, bucket_glob, W1, w1t);
  passB_kernel<<<NB, 256, 0, stream>>>(bucket_glob, bucket_cnt, row_ptr, colv);

  gemm1_kernel<<<(NN + 63) / 64, 256, 0, stream>>>(x, w1t, (unsigned short*)h1b,
                                                   att_src1, att_dst1, asrc1, adst1);
  l1_edge_kernel<<<(NN + 15) / 16, 256, 0, stream>>>(row_ptr, colv, h1b, asrc1, adst1,
                                                     b1, W2, att_src2, att_dst2,
                                                     gb, asrc2, adst2);
  l2_edge_kernel<<<(NN * 64 + 255) / 256, 256, 0, stream>>>(row_ptr, colv, gb, asrc2, adst2, b2, out);
}